// Round 3
// baseline (1088.821 us; speedup 1.0000x reference)
//
#include <hip/hip_runtime.h>
#include <stdint.h>

#define M_CH       384
#define TR         15
#define MARGIN     20
#define CHUNK_ROWS 16
#define BM_WORDS   192        // words per chunk = 16*384/32
#define WLCAP      262144

// ---------------- K0: neighbor lists ----------------
__global__ void nbr_kernel(const float* __restrict__ locs,
                           uint32_t* __restrict__ nbrCount,
                           uint16_t* __restrict__ nbrList) {
    __shared__ float lx[M_CH], ly[M_CH];
    int t = threadIdx.x;
    lx[t] = locs[2 * t];
    ly[t] = locs[2 * t + 1];
    __syncthreads();
    float x = lx[t], y = ly[t];
    int cnt = 0;
    for (int c = 0; c < M_CH; ++c) {
        float dx = x - lx[c], dy = y - ly[c];
        float d = sqrtf(dx * dx + dy * dy);
        if (d <= 100.0f) { nbrList[t * M_CH + cnt] = (uint16_t)c; cnt++; }
    }
    nbrCount[t] = cnt;
}

__global__ void init_kernel(uint32_t* __restrict__ wlCount) {
    if (threadIdx.x == 0) *wlCount = 0;
}

// ---------------- K1: streaming candidate pass ----------------
// Thread t handles samples [8t, 8t+8): two float4 loads, one byte-mask store.
// Margin boundaries (20*384, (N-20)*384) are multiples of 8 -> per-thread
// uniform margin test on the group index.
__global__ __launch_bounds__(256)
void cand_kernel(const float* __restrict__ traces, int mlo8, int mhi8,
                 uint8_t* __restrict__ candBytes,
                 uint32_t* __restrict__ wlCount,
                 uint32_t* __restrict__ worklist) {
    int t = blockIdx.x * 256 + threadIdx.x;      // byte/group index
    const float4* p = (const float4*)traces + (long)t * 2;
    float4 a = p[0], b = p[1];
    uint32_t m = 0;
    if (t >= mlo8 && t < mhi8) {
        m |= (a.x <= -3.0f) ? 1u   : 0u;
        m |= (a.y <= -3.0f) ? 2u   : 0u;
        m |= (a.z <= -3.0f) ? 4u   : 0u;
        m |= (a.w <= -3.0f) ? 8u   : 0u;
        m |= (b.x <= -3.0f) ? 16u  : 0u;
        m |= (b.y <= -3.0f) ? 32u  : 0u;
        m |= (b.z <= -3.0f) ? 64u  : 0u;
        m |= (b.w <= -3.0f) ? 128u : 0u;
    }
    candBytes[t] = (uint8_t)m;
    // push nonzero WORDS (4 bytes) to the unordered worklist
    uint64_t bal = __ballot(m != 0);
    int lane = threadIdx.x & 63;
    if ((lane & 3) == 0) {
        if ((bal >> lane) & 0xFull) {
            uint32_t slot = atomicAdd(wlCount, 1u);
            if (slot < WLCAP) worklist[slot] = (uint32_t)(t >> 2);
        }
    }
}

// ---------------- K2: validate rare candidates (wave per word) ----------
// valid  <=>  raw <= min over neighbors(incl self) x rows [r-15, r+15].
// Self is in its own neighbor list (dist 0), so raw==window-min is implied.
__global__ __launch_bounds__(256)
void validate_kernel(const float* __restrict__ traces,
                     const uint32_t* __restrict__ nbrCount,
                     const uint16_t* __restrict__ nbrList,
                     uint32_t* __restrict__ candBits,
                     const uint32_t* __restrict__ wlCount,
                     const uint32_t* __restrict__ worklist) {
    int lane = threadIdx.x & 63;
    int wid  = (blockIdx.x * 256 + threadIdx.x) >> 6;
    int nw   = (gridDim.x * 256) >> 6;
    uint32_t cnt = min(*wlCount, (uint32_t)WLCAP);
    for (uint32_t e = wid; e < cnt; e += nw) {
        uint32_t idx = worklist[e];
        uint32_t word = candBits[idx];         // uniform across wave
        int r  = (int)(idx / 12);              // 12 words per row
        int c0 = ((int)idx - r * 12) * 32;
        uint32_t tmp = word;
        while (tmp) {
            int b = __ffs(tmp) - 1;
            tmp &= tmp - 1;
            int c = c0 + b;
            float raw = traces[(long)r * M_CH + c];
            int nnb = (int)nbrCount[c];
            int total = nnb * 31;
            float mn = INFINITY;
            for (int i = lane; i < total; i += 64) {
                int j  = i / 31;
                int dt = i - j * 31 - TR;
                int c2 = (int)nbrList[c * M_CH + j];
                mn = fminf(mn, traces[(long)(r + dt) * M_CH + c2]);
            }
            #pragma unroll
            for (int off = 32; off; off >>= 1)
                mn = fminf(mn, __shfl_xor(mn, off, 64));
            if (raw > mn) word &= ~(1u << b);
        }
        if (lane == 0) candBits[idx] = word;
    }
}

// ---------------- K3: per-chunk popcount (wave per chunk) ----------------
__global__ void count_kernel(const uint32_t* __restrict__ candBits, int nchunk,
                             uint32_t* __restrict__ chunkCounts) {
    int lane  = threadIdx.x & 63;
    int chunk = (blockIdx.x * blockDim.x + threadIdx.x) >> 6;
    if (chunk >= nchunk) return;
    const uint32_t* wp = candBits + (long)chunk * BM_WORDS;
    int s = __popc(wp[lane]) + __popc(wp[lane + 64]) + __popc(wp[lane + 128]);
    #pragma unroll
    for (int off = 32; off; off >>= 1) s += __shfl_xor(s, off, 64);
    if (lane == 0) chunkCounts[chunk] = (uint32_t)s;
}

// ---------------- K4: exclusive prefix over chunk counts ----------------
__global__ void scan_kernel(const uint32_t* __restrict__ counts, int n,
                            uint32_t* __restrict__ prefix) {
    __shared__ uint32_t s[256];
    int t = threadIdx.x;
    int per = (n + 255) / 256;
    int lo = t * per, hi = min(lo + per, n);
    uint32_t sum = 0;
    for (int i = lo; i < hi; ++i) sum += counts[i];
    s[t] = sum;
    __syncthreads();
    for (int off = 1; off < 256; off <<= 1) {
        uint32_t v = (t >= off) ? s[t - off] : 0;
        __syncthreads();
        s[t] += v;
        __syncthreads();
    }
    uint32_t run = s[t] - sum;
    for (int i = lo; i < hi; ++i) { prefix[i] = run; run += counts[i]; }
    if (t == 255) prefix[n] = run;  // total
}

// ---------------- K5: ordered emit, one wave per chunk ----------------
__global__ void emit_kernel(const uint32_t* __restrict__ candBits,
                            const uint32_t* __restrict__ chunkPrefix,
                            int nchunk, int maxdet,
                            int* __restrict__ times, int* __restrict__ chans) {
    int wv = threadIdx.x >> 6;
    int lane = threadIdx.x & 63;
    int chunkId = blockIdx.x * 4 + wv;
    if (chunkId >= nchunk) return;

    const uint32_t* wp = candBits + (long)chunkId * BM_WORDS + lane * 3;
    uint32_t b0 = wp[0], b1 = wp[1], b2 = wp[2];
    int local = __popc(b0) + __popc(b1) + __popc(b2);

    int s = local;
    #pragma unroll
    for (int off = 1; off < 64; off <<= 1) {
        int v = __shfl_up(s, off, 64);
        if (lane >= off) s += v;
    }
    int base = (int)chunkPrefix[chunkId] + (s - local);
    int r0 = chunkId * CHUNK_ROWS;

    uint32_t words[3] = { b0, b1, b2 };
    #pragma unroll
    for (int q = 0; q < 3; ++q) {
        uint32_t x = words[q];
        int fbase = (lane * 3 + q) * 32;
        while (x) {
            int b = __ffs(x) - 1;
            x &= x - 1;
            int f = fbase + b;
            int n = f / M_CH;
            int ch = f - n * M_CH;
            if (base < maxdet) {
                times[base] = r0 + n;
                chans[base] = ch;
            }
            base++;
        }
    }
}

// ---------------- K6: fill tail with -1 ----------------
__global__ void fill_kernel(const uint32_t* __restrict__ totalPtr, int maxdet,
                            int* __restrict__ times, int* __restrict__ chans) {
    int i = blockIdx.x * blockDim.x + threadIdx.x;
    int total = (int)*totalPtr;
    if (i < maxdet && i >= total) { times[i] = -1; chans[i] = -1; }
}

extern "C" void kernel_launch(void* const* d_in, const int* in_sizes, int n_in,
                              void* d_out, int out_size, void* d_ws, size_t ws_size,
                              hipStream_t stream) {
    const float* traces = (const float*)d_in[0];
    const float* locs   = (const float*)d_in[1];
    const int M = M_CH;
    const int N = in_sizes[0] / M;            // 150000
    const int nsamp = N * M;                  // 57,600,000
    const int maxdet = out_size / 2;          // 100000
    int* times = (int*)d_out;
    int* chans = times + maxdet;

    const int nchunk = (N + CHUNK_ROWS - 1) / CHUNK_ROWS;   // 9375

    char* ws = (char*)d_ws;
    uint32_t* nbrCount    = (uint32_t*)(ws + 0);            // 1536 B
    uint16_t* nbrList     = (uint16_t*)(ws + 1536);         // 294912 B -> 296448
    uint32_t* wlCount     = (uint32_t*)(ws + 296448);       // 16 B     -> 296464
    uint32_t* chunkCounts = (uint32_t*)(ws + 296464);       // 37500 B  -> 333968 (padded)
    uint32_t* chunkPrefix = (uint32_t*)(ws + 333968);       // 37504 B  -> 371472
    uint32_t* worklist    = (uint32_t*)(ws + 371472);       // 1 MiB    -> 1420048
    uint32_t* candBits    = (uint32_t*)(ws + 1420048);      // 7.2 MB   -> ~8.62 MB total
    uint8_t*  candBytes   = (uint8_t*)candBits;

    init_kernel<<<1, 64, 0, stream>>>(wlCount);
    nbr_kernel<<<1, M_CH, 0, stream>>>(locs, nbrCount, nbrList);

    const int ngroups = nsamp / 8;            // 7,200,000
    const int mlo8 = (MARGIN * M) / 8;        // 960
    const int mhi8 = ((N - MARGIN) * M) / 8;
    cand_kernel<<<ngroups / 256, 256, 0, stream>>>(traces, mlo8, mhi8,
                                                   candBytes, wlCount, worklist);

    validate_kernel<<<2048, 256, 0, stream>>>(traces, nbrCount, nbrList,
                                              candBits, wlCount, worklist);

    count_kernel<<<(nchunk * 64 + 255) / 256, 256, 0, stream>>>(candBits, nchunk,
                                                                chunkCounts);

    scan_kernel<<<1, 256, 0, stream>>>(chunkCounts, nchunk, chunkPrefix);

    emit_kernel<<<(nchunk + 3) / 4, 256, 0, stream>>>(candBits, chunkPrefix,
                                                      nchunk, maxdet,
                                                      times, chans);

    fill_kernel<<<(maxdet + 255) / 256, 256, 0, stream>>>(chunkPrefix + nchunk,
                                                          maxdet, times, chans);
}

// Round 4
// 529.827 us; speedup vs baseline: 2.0550x; 2.0550x over previous
//
#include <hip/hip_runtime.h>
#include <stdint.h>

#define M_CH       384
#define TR         15
#define MARGIN     20
#define CHUNK_ROWS 16
#define BM_WORDS   192        // words per chunk = 16*384/32
#define WPR        12         // words per row = 384/32

// ---------------- K0: neighbor lists ----------------
__global__ void nbr_kernel(const float* __restrict__ locs,
                           uint32_t* __restrict__ nbrCount,
                           uint16_t* __restrict__ nbrList) {
    __shared__ float lx[M_CH], ly[M_CH];
    int t = threadIdx.x;
    lx[t] = locs[2 * t];
    ly[t] = locs[2 * t + 1];
    __syncthreads();
    float x = lx[t], y = ly[t];
    int cnt = 0;
    for (int c = 0; c < M_CH; ++c) {
        float dx = x - lx[c], dy = y - ly[c];
        float d = sqrtf(dx * dx + dy * dy);
        if (d <= 100.0f) { nbrList[t * M_CH + cnt] = (uint16_t)c; cnt++; }
    }
    nbrCount[t] = cnt;
}

// ---------------- K1: streaming candidate pass (no atomics) ----------------
// Thread w handles samples [32w, 32w+32): 8 independent float4 loads, one
// dword store of the threshold mask. Margin boundaries (20*384 and
// (N-20)*384 samples) are multiples of 32 -> uniform per-thread test.
__global__ __launch_bounds__(256)
void cand_kernel(const float* __restrict__ traces, int nwords, int mlo, int mhi,
                 uint32_t* __restrict__ candWords) {
    int w = blockIdx.x * 256 + threadIdx.x;
    if (w >= nwords) return;
    const float4* p = (const float4*)traces + (long)w * 8;
    float4 v[8];
    #pragma unroll
    for (int k = 0; k < 8; ++k) v[k] = p[k];
    uint32_t m = 0;
    #pragma unroll
    for (int k = 0; k < 8; ++k) {
        m |= (v[k].x <= -3.0f ? 1u : 0u) << (4 * k);
        m |= (v[k].y <= -3.0f ? 2u : 0u) << (4 * k);
        m |= (v[k].z <= -3.0f ? 4u : 0u) << (4 * k);
        m |= (v[k].w <= -3.0f ? 8u : 0u) << (4 * k);
    }
    if (w < mlo || w >= mhi) m = 0;
    candWords[w] = m;
}

// ---------------- K2: validate rare candidates (scan + wave-coop) --------
// Grid-stride: each wave loads 64 consecutive words, ballots nonzero, then
// cooperatively validates each nonzero word's bits: lanes split the
// nnb x 31 neighbor-window loads, shfl-xor min-reduce, clear failing bits.
// Self is in its own neighbor list (dist 0), so raw==window-min is implied.
__global__ __launch_bounds__(256)
void validate_kernel(const float* __restrict__ traces,
                     const uint32_t* __restrict__ nbrCount,
                     const uint16_t* __restrict__ nbrList,
                     uint32_t* __restrict__ candWords, int nwords) {
    int lane = threadIdx.x & 63;
    int wid  = (blockIdx.x * 256 + threadIdx.x) >> 6;
    int nwv  = (gridDim.x * 256) >> 6;
    for (long base = (long)wid * 64; base < nwords; base += (long)nwv * 64) {
        int myIdx = (int)base + lane;
        uint32_t myw = (myIdx < nwords) ? candWords[myIdx] : 0u;
        uint64_t mask = __ballot(myw != 0u);
        while (mask) {
            int b = __ffsll((unsigned long long)mask) - 1;
            mask &= mask - 1;
            uint32_t word = (uint32_t)__shfl((int)myw, b, 64);
            int widx = (int)base + b;
            int r  = widx / WPR;
            int c0 = (widx - r * WPR) * 32;
            uint32_t out = word, tmp = word;
            while (tmp) {
                int bit = __ffs(tmp) - 1;
                tmp &= tmp - 1;
                int c = c0 + bit;
                float raw = traces[(long)r * M_CH + c];   // wave-uniform, broadcast
                int nnb = (int)nbrCount[c];
                int total = nnb * 31;
                float mn = INFINITY;
                for (int i = lane; i < total; i += 64) {
                    int j  = i / 31;
                    int dt = i - j * 31 - TR;
                    int c2 = (int)nbrList[c * M_CH + j];
                    mn = fminf(mn, traces[(long)(r + dt) * M_CH + c2]);
                }
                #pragma unroll
                for (int off = 32; off; off >>= 1)
                    mn = fminf(mn, __shfl_xor(mn, off, 64));
                if (raw > mn) out &= ~(1u << bit);
            }
            if (lane == b && out != word) candWords[widx] = out;
        }
    }
}

// ---------------- K3: per-chunk popcount (wave per chunk) ----------------
__global__ void count_kernel(const uint32_t* __restrict__ candWords, int nchunk,
                             uint32_t* __restrict__ chunkCounts) {
    int lane  = threadIdx.x & 63;
    int chunk = (blockIdx.x * blockDim.x + threadIdx.x) >> 6;
    if (chunk >= nchunk) return;
    const uint32_t* wp = candWords + (long)chunk * BM_WORDS;
    int s = __popc(wp[lane]) + __popc(wp[lane + 64]) + __popc(wp[lane + 128]);
    #pragma unroll
    for (int off = 32; off; off >>= 1) s += __shfl_xor(s, off, 64);
    if (lane == 0) chunkCounts[chunk] = (uint32_t)s;
}

// ---------------- K4: exclusive prefix over chunk counts ----------------
__global__ void scan_kernel(const uint32_t* __restrict__ counts, int n,
                            uint32_t* __restrict__ prefix) {
    __shared__ uint32_t s[256];
    int t = threadIdx.x;
    int per = (n + 255) / 256;
    int lo = t * per, hi = min(lo + per, n);
    uint32_t sum = 0;
    for (int i = lo; i < hi; ++i) sum += counts[i];
    s[t] = sum;
    __syncthreads();
    for (int off = 1; off < 256; off <<= 1) {
        uint32_t v = (t >= off) ? s[t - off] : 0;
        __syncthreads();
        s[t] += v;
        __syncthreads();
    }
    uint32_t run = s[t] - sum;
    for (int i = lo; i < hi; ++i) { prefix[i] = run; run += counts[i]; }
    if (t == 255) prefix[n] = run;  // total
}

// ---------------- K5: ordered emit, one wave per chunk ----------------
__global__ void emit_kernel(const uint32_t* __restrict__ candWords,
                            const uint32_t* __restrict__ chunkPrefix,
                            int nchunk, int maxdet,
                            int* __restrict__ times, int* __restrict__ chans) {
    int wv = threadIdx.x >> 6;
    int lane = threadIdx.x & 63;
    int chunkId = blockIdx.x * 4 + wv;
    if (chunkId >= nchunk) return;

    const uint32_t* wp = candWords + (long)chunkId * BM_WORDS + lane * 3;
    uint32_t b0 = wp[0], b1 = wp[1], b2 = wp[2];
    int local = __popc(b0) + __popc(b1) + __popc(b2);

    int s = local;
    #pragma unroll
    for (int off = 1; off < 64; off <<= 1) {
        int v = __shfl_up(s, off, 64);
        if (lane >= off) s += v;
    }
    int base = (int)chunkPrefix[chunkId] + (s - local);
    int r0 = chunkId * CHUNK_ROWS;

    uint32_t words[3] = { b0, b1, b2 };
    #pragma unroll
    for (int q = 0; q < 3; ++q) {
        uint32_t x = words[q];
        int fbase = (lane * 3 + q) * 32;
        while (x) {
            int b = __ffs(x) - 1;
            x &= x - 1;
            int f = fbase + b;
            int n = f / M_CH;
            int ch = f - n * M_CH;
            if (base < maxdet) {
                times[base] = r0 + n;
                chans[base] = ch;
            }
            base++;
        }
    }
}

// ---------------- K6: fill tail with -1 ----------------
__global__ void fill_kernel(const uint32_t* __restrict__ totalPtr, int maxdet,
                            int* __restrict__ times, int* __restrict__ chans) {
    int i = blockIdx.x * blockDim.x + threadIdx.x;
    int total = (int)*totalPtr;
    if (i < maxdet && i >= total) { times[i] = -1; chans[i] = -1; }
}

extern "C" void kernel_launch(void* const* d_in, const int* in_sizes, int n_in,
                              void* d_out, int out_size, void* d_ws, size_t ws_size,
                              hipStream_t stream) {
    const float* traces = (const float*)d_in[0];
    const float* locs   = (const float*)d_in[1];
    const int M = M_CH;
    const int N = in_sizes[0] / M;            // 150000
    const int nsamp = N * M;                  // 57,600,000
    const int maxdet = out_size / 2;          // 100000
    int* times = (int*)d_out;
    int* chans = times + maxdet;

    const int nwords = nsamp / 32;                          // 1,800,000
    const int nchunk = (N + CHUNK_ROWS - 1) / CHUNK_ROWS;   // 9375

    char* ws = (char*)d_ws;
    uint32_t* nbrCount    = (uint32_t*)(ws + 0);            // 1536 B
    uint16_t* nbrList     = (uint16_t*)(ws + 1536);         // 294912 -> 296448
    uint32_t* chunkCounts = (uint32_t*)(ws + 296448);       // 37500  -> 333948
    uint32_t* chunkPrefix = (uint32_t*)(ws + 333952);       // 37504  -> 371456
    uint32_t* candWords   = (uint32_t*)(ws + 371456);       // 7.2 MB

    nbr_kernel<<<1, M_CH, 0, stream>>>(locs, nbrCount, nbrList);

    const int mlo = (MARGIN * M) / 32;          // 240
    const int mhi = ((N - MARGIN) * M) / 32;    // 1,799,760
    cand_kernel<<<(nwords + 255) / 256, 256, 0, stream>>>(traces, nwords,
                                                          mlo, mhi, candWords);

    validate_kernel<<<2048, 256, 0, stream>>>(traces, nbrCount, nbrList,
                                              candWords, nwords);

    count_kernel<<<(nchunk * 64 + 255) / 256, 256, 0, stream>>>(candWords, nchunk,
                                                                chunkCounts);

    scan_kernel<<<1, 256, 0, stream>>>(chunkCounts, nchunk, chunkPrefix);

    emit_kernel<<<(nchunk + 3) / 4, 256, 0, stream>>>(candWords, chunkPrefix,
                                                      nchunk, maxdet,
                                                      times, chans);

    fill_kernel<<<(maxdet + 255) / 256, 256, 0, stream>>>(chunkPrefix + nchunk,
                                                          maxdet, times, chans);
}

// Round 5
// 428.138 us; speedup vs baseline: 2.5432x; 1.2375x over previous
//
#include <hip/hip_runtime.h>
#include <stdint.h>

#define M_CH       384
#define TR         15
#define MARGIN     20
#define CHUNK_ROWS 16
#define BM_WORDS   192        // words per chunk = 16*384/32
#define WPR        12         // words per row = 384/32

// spread 8 bits of x to positions 0,4,8,...,28
__device__ __forceinline__ uint32_t spread4(uint32_t x) {
    x = (x | (x << 12)) & 0x000F000Fu;
    x = (x | (x << 6))  & 0x03030303u;
    x = (x | (x << 3))  & 0x11111111u;
    return x;
}

// ---------------- K0: per-channel neighbor word-masks ----------------
__global__ void nbr_kernel(const float* __restrict__ locs,
                           uint32_t* __restrict__ nEntries,
                           uint8_t* __restrict__ entryWord,
                           uint32_t* __restrict__ entryMask) {
    __shared__ float lx[M_CH], ly[M_CH];
    int t = threadIdx.x;
    lx[t] = locs[2 * t];
    ly[t] = locs[2 * t + 1];
    __syncthreads();
    float x = lx[t], y = ly[t];
    uint32_t m[WPR];
    #pragma unroll
    for (int k = 0; k < WPR; ++k) m[k] = 0;
    for (int c = 0; c < M_CH; ++c) {
        float dx = x - lx[c], dy = y - ly[c];
        if (sqrtf(dx * dx + dy * dy) <= 100.0f) m[c >> 5] |= 1u << (c & 31);
    }
    int ne = 0;
    #pragma unroll
    for (int k = 0; k < WPR; ++k) {
        if (m[k]) {
            entryWord[t * WPR + ne] = (uint8_t)k;
            entryMask[t * WPR + ne] = m[k];
            ne++;
        }
    }
    nEntries[t] = (uint32_t)ne;
}

// ---------------- K1: streaming threshold pass (pure mask, NO margin) ----
// One float4 per lane (fully coalesced 1 KB per wave-instr). Words are
// assembled from 4 ballots via bit-spread; lanes 0-7 store 8 words/wave.
__global__ __launch_bounds__(256)
void cand_kernel(const float* __restrict__ traces, long n4, long nwords,
                 uint32_t* __restrict__ candWords) {
    const int lane = threadIdx.x & 63;
    const long stride = (long)gridDim.x * 256;
    for (long i = (long)blockIdx.x * 256 + threadIdx.x; i - lane < n4; i += stride) {
        float4 v = make_float4(0.f, 0.f, 0.f, 0.f);
        if (i < n4) v = ((const float4*)traces)[i];
        uint64_t B0 = __ballot(v.x <= -3.0f);
        uint64_t B1 = __ballot(v.y <= -3.0f);
        uint64_t B2 = __ballot(v.z <= -3.0f);
        uint64_t B3 = __ballot(v.w <= -3.0f);
        if (lane < 8) {
            uint32_t b0 = (uint32_t)(B0 >> (8 * lane)) & 0xFFu;
            uint32_t b1 = (uint32_t)(B1 >> (8 * lane)) & 0xFFu;
            uint32_t b2 = (uint32_t)(B2 >> (8 * lane)) & 0xFFu;
            uint32_t b3 = (uint32_t)(B3 >> (8 * lane)) & 0xFFu;
            uint32_t word = spread4(b0) | (spread4(b1) << 1)
                          | (spread4(b2) << 2) | (spread4(b3) << 3);
            long wIdx = (i - lane) / 8 + lane;
            if (wIdx < nwords) candWords[wIdx] = word;
        }
    }
}

// ---------------- K2: validate against the MASK, not the traces -----------
// A competitor v < raw <= -3 necessarily has its threshold bit set, so we
// only scan mask words (7.2 MB, cache-resident) and touch traces on the
// rare hit. Margin applied here; result written to a separate validOut
// (in-place clearing would race with competitor reads).
__global__ __launch_bounds__(256)
void validate_kernel(const float* __restrict__ traces, int N, long nwords,
                     const uint32_t* __restrict__ nEntries,
                     const uint8_t* __restrict__ entryWord,
                     const uint32_t* __restrict__ entryMask,
                     const uint32_t* __restrict__ candWords,
                     uint32_t* __restrict__ validOut) {
    long w = (long)blockIdx.x * 256 + threadIdx.x;
    if (w >= nwords) return;
    uint32_t word = candWords[w];
    uint32_t out = 0;
    if (word) {
        int r  = (int)(w / WPR);
        int cw = (int)(w - (long)r * WPR);
        if (r >= MARGIN && r < N - MARGIN) {
            out = word;
            uint32_t tmp = word;
            while (tmp) {
                int bit = __ffs(tmp) - 1;
                tmp &= tmp - 1;
                int c = cw * 32 + bit;
                float raw = traces[(long)r * M_CH + c];
                int ne = (int)nEntries[c];
                bool bad = false;
                for (int k = 0; k < ne; ++k) {
                    int wi = (int)entryWord[c * WPR + k];
                    uint32_t em = entryMask[c * WPR + k];
                    const uint32_t* colp = candWords + (long)(r - TR) * WPR + wi;
                    uint32_t hitRows = 0;
                    #pragma unroll
                    for (int dt = 0; dt < 31; ++dt) {
                        uint32_t h = colp[(long)dt * WPR] & em;
                        hitRows |= (h ? 1u : 0u) << dt;
                    }
                    if (hitRows) {                       // rare slow path
                        while (hitRows) {
                            int dt = __ffs(hitRows) - 1;
                            hitRows &= hitRows - 1;
                            uint32_t h = colp[(long)dt * WPR] & em;
                            while (h) {
                                int b2 = __ffs(h) - 1;
                                h &= h - 1;
                                float v = traces[(long)(r - TR + dt) * M_CH + wi * 32 + b2];
                                if (v < raw) bad = true;
                            }
                        }
                        if (bad) break;
                    }
                }
                if (bad) out &= ~(1u << bit);
            }
        }
    }
    validOut[w] = out;
}

// ---------------- K3: per-chunk popcount (wave per chunk) ----------------
__global__ void count_kernel(const uint32_t* __restrict__ validOut, int nchunk,
                             uint32_t* __restrict__ chunkCounts) {
    int lane  = threadIdx.x & 63;
    int chunk = (blockIdx.x * blockDim.x + threadIdx.x) >> 6;
    if (chunk >= nchunk) return;
    const uint32_t* wp = validOut + (long)chunk * BM_WORDS;
    int s = __popc(wp[lane]) + __popc(wp[lane + 64]) + __popc(wp[lane + 128]);
    #pragma unroll
    for (int off = 32; off; off >>= 1) s += __shfl_xor(s, off, 64);
    if (lane == 0) chunkCounts[chunk] = (uint32_t)s;
}

// ---------------- K4: exclusive prefix over chunk counts ----------------
__global__ void scan_kernel(const uint32_t* __restrict__ counts, int n,
                            uint32_t* __restrict__ prefix) {
    __shared__ uint32_t s[256];
    int t = threadIdx.x;
    int per = (n + 255) / 256;
    int lo = t * per, hi = min(lo + per, n);
    uint32_t sum = 0;
    for (int i = lo; i < hi; ++i) sum += counts[i];
    s[t] = sum;
    __syncthreads();
    for (int off = 1; off < 256; off <<= 1) {
        uint32_t v = (t >= off) ? s[t - off] : 0;
        __syncthreads();
        s[t] += v;
        __syncthreads();
    }
    uint32_t run = s[t] - sum;
    for (int i = lo; i < hi; ++i) { prefix[i] = run; run += counts[i]; }
    if (t == 255) prefix[n] = run;  // total
}

// ---------------- K5: ordered emit, one wave per chunk ----------------
__global__ void emit_kernel(const uint32_t* __restrict__ validOut,
                            const uint32_t* __restrict__ chunkPrefix,
                            int nchunk, int maxdet,
                            int* __restrict__ times, int* __restrict__ chans) {
    int wv = threadIdx.x >> 6;
    int lane = threadIdx.x & 63;
    int chunkId = blockIdx.x * 4 + wv;
    if (chunkId >= nchunk) return;

    const uint32_t* wp = validOut + (long)chunkId * BM_WORDS + lane * 3;
    uint32_t b0 = wp[0], b1 = wp[1], b2 = wp[2];
    int local = __popc(b0) + __popc(b1) + __popc(b2);

    int s = local;
    #pragma unroll
    for (int off = 1; off < 64; off <<= 1) {
        int v = __shfl_up(s, off, 64);
        if (lane >= off) s += v;
    }
    int base = (int)chunkPrefix[chunkId] + (s - local);
    int r0 = chunkId * CHUNK_ROWS;

    uint32_t words[3] = { b0, b1, b2 };
    #pragma unroll
    for (int q = 0; q < 3; ++q) {
        uint32_t x = words[q];
        int fbase = (lane * 3 + q) * 32;
        while (x) {
            int b = __ffs(x) - 1;
            x &= x - 1;
            int f = fbase + b;
            int n = f / M_CH;
            int ch = f - n * M_CH;
            if (base < maxdet) {
                times[base] = r0 + n;
                chans[base] = ch;
            }
            base++;
        }
    }
}

// ---------------- K6: fill tail with -1 ----------------
__global__ void fill_kernel(const uint32_t* __restrict__ totalPtr, int maxdet,
                            int* __restrict__ times, int* __restrict__ chans) {
    int i = blockIdx.x * blockDim.x + threadIdx.x;
    int total = (int)*totalPtr;
    if (i < maxdet && i >= total) { times[i] = -1; chans[i] = -1; }
}

extern "C" void kernel_launch(void* const* d_in, const int* in_sizes, int n_in,
                              void* d_out, int out_size, void* d_ws, size_t ws_size,
                              hipStream_t stream) {
    const float* traces = (const float*)d_in[0];
    const float* locs   = (const float*)d_in[1];
    const int M = M_CH;
    const int N = in_sizes[0] / M;            // 150000
    const long nsamp = (long)N * M;           // 57,600,000
    const int maxdet = out_size / 2;          // 100000
    int* times = (int*)d_out;
    int* chans = times + maxdet;

    const long n4     = nsamp / 4;                          // 14,400,000
    const long nwords = nsamp / 32;                         // 1,800,000
    const int  nchunk = (N + CHUNK_ROWS - 1) / CHUNK_ROWS;  // 9375

    char* ws = (char*)d_ws;
    uint32_t* nEntries    = (uint32_t*)(ws + 0);            // 1536
    uint8_t*  entryWord   = (uint8_t*)(ws + 1536);          // 4608   -> 6144
    uint32_t* entryMask   = (uint32_t*)(ws + 6144);         // 18432  -> 24576
    uint32_t* chunkCounts = (uint32_t*)(ws + 24576);        // 37500  -> 62080 (pad)
    uint32_t* chunkPrefix = (uint32_t*)(ws + 62080);        // 37504  -> 99584
    uint32_t* candWords   = (uint32_t*)(ws + 99584);        // 7.2 MB -> 7299584
    uint32_t* validOut    = (uint32_t*)(ws + 7299584);      // 7.2 MB -> 14.5 MB

    nbr_kernel<<<1, M_CH, 0, stream>>>(locs, nEntries, entryWord, entryMask);

    cand_kernel<<<2048, 256, 0, stream>>>(traces, n4, nwords, candWords);

    validate_kernel<<<(int)((nwords + 255) / 256), 256, 0, stream>>>(
        traces, N, nwords, nEntries, entryWord, entryMask, candWords, validOut);

    count_kernel<<<(nchunk * 64 + 255) / 256, 256, 0, stream>>>(validOut, nchunk,
                                                                chunkCounts);

    scan_kernel<<<1, 256, 0, stream>>>(chunkCounts, nchunk, chunkPrefix);

    emit_kernel<<<(nchunk + 3) / 4, 256, 0, stream>>>(validOut, chunkPrefix,
                                                      nchunk, maxdet,
                                                      times, chans);

    fill_kernel<<<(maxdet + 255) / 256, 256, 0, stream>>>(chunkPrefix + nchunk,
                                                          maxdet, times, chans);
}

// Round 6
// 425.637 us; speedup vs baseline: 2.5581x; 1.0059x over previous
//
#include <hip/hip_runtime.h>
#include <stdint.h>

#define M_CH       384
#define TR         15
#define MARGIN     20
#define CHUNK_ROWS 16
#define BM_WORDS   192        // words per chunk = 16*384/32
#define WPR        12         // words per row = 384/32

// spread 8 bits of x to positions 0,4,8,...,28
__device__ __forceinline__ uint32_t spread4(uint32_t x) {
    x = (x | (x << 12)) & 0x000F000Fu;
    x = (x | (x << 6))  & 0x03030303u;
    x = (x | (x << 3))  & 0x11111111u;
    return x;
}

// ---------------- K0: per-channel neighbor word-masks ----------------
__global__ void nbr_kernel(const float* __restrict__ locs,
                           uint32_t* __restrict__ nEntries,
                           uint8_t* __restrict__ entryWord,
                           uint32_t* __restrict__ entryMask) {
    __shared__ float lx[M_CH], ly[M_CH];
    int t = threadIdx.x;
    lx[t] = locs[2 * t];
    ly[t] = locs[2 * t + 1];
    __syncthreads();
    float x = lx[t], y = ly[t];
    uint32_t m[WPR];
    #pragma unroll
    for (int k = 0; k < WPR; ++k) m[k] = 0;
    for (int c = 0; c < M_CH; ++c) {
        float dx = x - lx[c], dy = y - ly[c];
        if (sqrtf(dx * dx + dy * dy) <= 100.0f) m[c >> 5] |= 1u << (c & 31);
    }
    int ne = 0;
    #pragma unroll
    for (int k = 0; k < WPR; ++k) {
        if (m[k]) {
            entryWord[t * WPR + ne] = (uint8_t)k;
            entryMask[t * WPR + ne] = m[k];
            ne++;
        }
    }
    nEntries[t] = (uint32_t)ne;
}

// ---------------- K1: streaming threshold pass ----------------
// Wave handles 256 contiguous float4s (1024 samples = 32 words):
// 4 coalesced 1-KB loads in flight, 16 ballots, lanes 0-31 store 32
// contiguous words (128-B coalesced store). No margin here (competitors
// outside margin must keep their bits).
__global__ __launch_bounds__(256)
void cand_kernel(const float* __restrict__ traces, long n4, long nwords,
                 uint32_t* __restrict__ candWords) {
    const int lane = threadIdx.x & 63;
    const long wv = (((long)blockIdx.x * 256) + threadIdx.x) >> 6;
    const long fb = wv * 256;                  // first float4 of this wave
    uint64_t B00,B01,B02,B03, B10,B11,B12,B13,
             B20,B21,B22,B23, B30,B31,B32,B33;
    {
        float4 v0 = make_float4(0,0,0,0), v1 = v0, v2 = v0, v3 = v0;
        long i0 = fb + 0 * 64 + lane;
        long i1 = fb + 1 * 64 + lane;
        long i2 = fb + 2 * 64 + lane;
        long i3 = fb + 3 * 64 + lane;
        if (i0 < n4) v0 = ((const float4*)traces)[i0];
        if (i1 < n4) v1 = ((const float4*)traces)[i1];
        if (i2 < n4) v2 = ((const float4*)traces)[i2];
        if (i3 < n4) v3 = ((const float4*)traces)[i3];
        B00 = __ballot(v0.x <= -3.0f); B01 = __ballot(v0.y <= -3.0f);
        B02 = __ballot(v0.z <= -3.0f); B03 = __ballot(v0.w <= -3.0f);
        B10 = __ballot(v1.x <= -3.0f); B11 = __ballot(v1.y <= -3.0f);
        B12 = __ballot(v1.z <= -3.0f); B13 = __ballot(v1.w <= -3.0f);
        B20 = __ballot(v2.x <= -3.0f); B21 = __ballot(v2.y <= -3.0f);
        B22 = __ballot(v2.z <= -3.0f); B23 = __ballot(v2.w <= -3.0f);
        B30 = __ballot(v3.x <= -3.0f); B31 = __ballot(v3.y <= -3.0f);
        B32 = __ballot(v3.z <= -3.0f); B33 = __ballot(v3.w <= -3.0f);
    }
    if (lane < 32) {
        int k  = lane >> 3;           // which load group
        int sh = (lane & 7) * 8;      // which byte of the ballot
        uint64_t b0 = (k & 2) ? ((k & 1) ? B30 : B20) : ((k & 1) ? B10 : B00);
        uint64_t b1 = (k & 2) ? ((k & 1) ? B31 : B21) : ((k & 1) ? B11 : B01);
        uint64_t b2 = (k & 2) ? ((k & 1) ? B32 : B22) : ((k & 1) ? B12 : B02);
        uint64_t b3 = (k & 2) ? ((k & 1) ? B33 : B23) : ((k & 1) ? B13 : B03);
        uint32_t w = spread4((uint32_t)(b0 >> sh) & 0xFFu)
                   | (spread4((uint32_t)(b1 >> sh) & 0xFFu) << 1)
                   | (spread4((uint32_t)(b2 >> sh) & 0xFFu) << 2)
                   | (spread4((uint32_t)(b3 >> sh) & 0xFFu) << 3);
        long wIdx = wv * 32 + lane;
        if (wIdx < nwords) candWords[wIdx] = w;
    }
}

// ---------------- K2: validate against the MASK + per-chunk count --------
// A competitor v < raw <= -3 necessarily has its threshold bit set, so we
// scan mask words (7.2 MB, cache-resident) and touch traces only on the
// rare hit. Margin applied here; result to separate validOut (in-place
// clearing would race). Block = 192 threads = exactly one 16-row chunk;
// per-block popcount reduce -> chunkCounts[blockIdx].
__global__ __launch_bounds__(192)
void validate_count_kernel(const float* __restrict__ traces, int N, long nwords,
                           const uint32_t* __restrict__ nEntries,
                           const uint8_t* __restrict__ entryWord,
                           const uint32_t* __restrict__ entryMask,
                           const uint32_t* __restrict__ candWords,
                           uint32_t* __restrict__ validOut,
                           uint32_t* __restrict__ chunkCounts) {
    __shared__ uint32_t red[3];
    const int t = threadIdx.x;
    const long w = (long)blockIdx.x * BM_WORDS + t;
    uint32_t out = 0;
    if (w < nwords) {
        uint32_t word = candWords[w];
        if (word) {
            int r  = (int)(w / WPR);
            int cw = (int)(w - (long)r * WPR);
            if (r >= MARGIN && r < N - MARGIN) {
                out = word;
                uint32_t tmp = word;
                while (tmp) {
                    int bit = __ffs(tmp) - 1;
                    tmp &= tmp - 1;
                    int c = cw * 32 + bit;
                    float raw = traces[(long)r * M_CH + c];
                    int ne = (int)nEntries[c];
                    bool bad = false;
                    for (int k = 0; k < ne; ++k) {
                        int wi = (int)entryWord[c * WPR + k];
                        uint32_t em = entryMask[c * WPR + k];
                        const uint32_t* colp = candWords + (long)(r - TR) * WPR + wi;
                        uint32_t hitRows = 0;
                        #pragma unroll
                        for (int dt = 0; dt < 31; ++dt) {
                            uint32_t h = colp[(long)dt * WPR] & em;
                            hitRows |= (h ? 1u : 0u) << dt;
                        }
                        if (hitRows) {                       // rare slow path
                            while (hitRows) {
                                int dt = __ffs(hitRows) - 1;
                                hitRows &= hitRows - 1;
                                uint32_t h = colp[(long)dt * WPR] & em;
                                while (h) {
                                    int b2 = __ffs(h) - 1;
                                    h &= h - 1;
                                    float v = traces[(long)(r - TR + dt) * M_CH + wi * 32 + b2];
                                    if (v < raw) bad = true;
                                }
                            }
                            if (bad) break;
                        }
                    }
                    if (bad) out &= ~(1u << bit);
                }
            }
        }
        validOut[w] = out;
    }
    int pc = __popc(out);
    #pragma unroll
    for (int off = 32; off; off >>= 1) pc += __shfl_xor(pc, off, 64);
    if ((t & 63) == 0) red[t >> 6] = (uint32_t)pc;
    __syncthreads();
    if (t == 0) chunkCounts[blockIdx.x] = red[0] + red[1] + red[2];
}

// ---------------- K3: exclusive prefix over chunk counts ----------------
__global__ void scan_kernel(const uint32_t* __restrict__ counts, int n,
                            uint32_t* __restrict__ prefix) {
    __shared__ uint32_t s[256];
    int t = threadIdx.x;
    int per = (n + 255) / 256;
    int lo = t * per, hi = min(lo + per, n);
    uint32_t sum = 0;
    for (int i = lo; i < hi; ++i) sum += counts[i];
    s[t] = sum;
    __syncthreads();
    for (int off = 1; off < 256; off <<= 1) {
        uint32_t v = (t >= off) ? s[t - off] : 0;
        __syncthreads();
        s[t] += v;
        __syncthreads();
    }
    uint32_t run = s[t] - sum;
    for (int i = lo; i < hi; ++i) { prefix[i] = run; run += counts[i]; }
    if (t == 255) prefix[n] = run;  // total
}

// ---------------- K4: ordered emit (wave per chunk) + tail fill ----------
__global__ void emit_fill_kernel(const uint32_t* __restrict__ validOut,
                                 const uint32_t* __restrict__ chunkPrefix,
                                 int nchunk, int emitBlocks, int maxdet,
                                 int* __restrict__ times, int* __restrict__ chans) {
    if ((int)blockIdx.x >= emitBlocks) {
        // fill role
        int i = ((int)blockIdx.x - emitBlocks) * 256 + threadIdx.x;
        int total = (int)chunkPrefix[nchunk];
        if (i < maxdet && i >= total) { times[i] = -1; chans[i] = -1; }
        return;
    }
    int wv = threadIdx.x >> 6;
    int lane = threadIdx.x & 63;
    int chunkId = blockIdx.x * 4 + wv;
    if (chunkId >= nchunk) return;

    const uint32_t* wp = validOut + (long)chunkId * BM_WORDS + lane * 3;
    uint32_t b0 = wp[0], b1 = wp[1], b2 = wp[2];
    int local = __popc(b0) + __popc(b1) + __popc(b2);

    int s = local;
    #pragma unroll
    for (int off = 1; off < 64; off <<= 1) {
        int v = __shfl_up(s, off, 64);
        if (lane >= off) s += v;
    }
    int base = (int)chunkPrefix[chunkId] + (s - local);
    int r0 = chunkId * CHUNK_ROWS;

    uint32_t words[3] = { b0, b1, b2 };
    #pragma unroll
    for (int q = 0; q < 3; ++q) {
        uint32_t x = words[q];
        int fbase = (lane * 3 + q) * 32;
        while (x) {
            int b = __ffs(x) - 1;
            x &= x - 1;
            int f = fbase + b;
            int n = f / M_CH;
            int ch = f - n * M_CH;
            if (base < maxdet) {
                times[base] = r0 + n;
                chans[base] = ch;
            }
            base++;
        }
    }
}

extern "C" void kernel_launch(void* const* d_in, const int* in_sizes, int n_in,
                              void* d_out, int out_size, void* d_ws, size_t ws_size,
                              hipStream_t stream) {
    const float* traces = (const float*)d_in[0];
    const float* locs   = (const float*)d_in[1];
    const int M = M_CH;
    const int N = in_sizes[0] / M;            // 150000
    const long nsamp = (long)N * M;           // 57,600,000
    const int maxdet = out_size / 2;          // 100000
    int* times = (int*)d_out;
    int* chans = times + maxdet;

    const long n4     = nsamp / 4;                          // 14,400,000
    const long nwords = nsamp / 32;                         // 1,800,000
    const int  nchunk = (N + CHUNK_ROWS - 1) / CHUNK_ROWS;  // 9375

    char* ws = (char*)d_ws;
    uint32_t* nEntries    = (uint32_t*)(ws + 0);            // 1536
    uint8_t*  entryWord   = (uint8_t*)(ws + 1536);          // 4608   -> 6144
    uint32_t* entryMask   = (uint32_t*)(ws + 6144);         // 18432  -> 24576
    uint32_t* chunkCounts = (uint32_t*)(ws + 24576);        // 37500  -> 62080 (pad)
    uint32_t* chunkPrefix = (uint32_t*)(ws + 62080);        // 37504  -> 99584
    uint32_t* candWords   = (uint32_t*)(ws + 99584);        // 7.2 MB -> 7299584
    uint32_t* validOut    = (uint32_t*)(ws + 7299584);      // 7.2 MB -> 14.5 MB

    nbr_kernel<<<1, M_CH, 0, stream>>>(locs, nEntries, entryWord, entryMask);

    // 1024 samples (32 words) per wave; 4 waves per block
    const long nwaves = (nwords + 31) / 32;                 // 56250
    const int  cblocks = (int)((nwaves + 3) / 4);           // 14063
    cand_kernel<<<cblocks, 256, 0, stream>>>(traces, n4, nwords, candWords);

    validate_count_kernel<<<nchunk, BM_WORDS, 0, stream>>>(
        traces, N, nwords, nEntries, entryWord, entryMask, candWords,
        validOut, chunkCounts);

    scan_kernel<<<1, 256, 0, stream>>>(chunkCounts, nchunk, chunkPrefix);

    const int emitBlocks = (nchunk + 3) / 4;                // 2344
    const int fillBlocks = (maxdet + 255) / 256;            // 391
    emit_fill_kernel<<<emitBlocks + fillBlocks, 256, 0, stream>>>(
        validOut, chunkPrefix, nchunk, emitBlocks, maxdet, times, chans);
}